// Round 8
// baseline (1219.136 us; speedup 1.0000x reference)
//
#include <hip/hip_runtime.h>
#include <hip/hip_cooperative_groups.h>
#include <math.h>

namespace cg = cooperative_groups;

#define N_NODES 30000
#define N_EDGES 240000
#define NETYPES 8
#define NGRAPHS 64
#define NLAYERS 3

typedef __attribute__((ext_vector_type(8))) short short8;
typedef __attribute__((ext_vector_type(8))) unsigned short ushort8;
typedef __attribute__((ext_vector_type(4))) float f32x4;

// ---- bf16 split helpers (round-to-nearest-even) ----
__device__ __forceinline__ unsigned short f2bf(float f) {
  union { float f; unsigned u; } v; v.f = f;
  unsigned r = v.u + 0x7FFF + ((v.u >> 16) & 1);
  return (unsigned short)(r >> 16);
}
__device__ __forceinline__ float bf2f(unsigned short h) {
  union { unsigned u; float f; } v; v.u = ((unsigned)h) << 16;
  return v.f;
}

__device__ __forceinline__ void async_g2l(const unsigned short* g, unsigned short* l) {
  __builtin_amdgcn_global_load_lds(
      (const __attribute__((address_space(1))) void*)g,
      (__attribute__((address_space(3))) void*)l, 16, 0, 0);
}

// =====================================================================
// Kernel 1: fused prologue (cooperative)
//   phase0: zero deg/gacc, bias concat, x hi/lo split, W transpose+cvt
//   phase1: degree count   phase2: prefix scan (block 0)   phase3: scatter
// =====================================================================
struct PreArgs {
  const int *src, *dst, *etype;
  const float *Wq, *Wk, *Wv, *bq, *bk, *bv, *x;
  int *deg, *rowstart, *cursor, *packed;
  unsigned short *wthi, *xhi, *xlo;
  float *bcat, *gacc;
};

__global__ __launch_bounds__(256) void k_pre(PreArgs P) {
  cg::grid_group grid = cg::this_grid();
  __shared__ float tile[32][33];
  __shared__ int wsum4[4];
  int b = blockIdx.x, t = threadIdx.x, nb = gridDim.x;
  int gid = b * 256 + t, gstride = nb * 256;

  // ---- phase 0 ----
  for (int i = gid; i < N_NODES; i += gstride) P.deg[i] = 0;
  for (int i = gid; i < NGRAPHS * 256; i += gstride) P.gacc[i] = 0.f;
  for (int i = gid; i < NLAYERS * 768; i += gstride) {
    int n = i % 768, l = i / 768;
    int which = n >> 8, col = n & 255;
    const float* bb = (which == 0) ? P.bq : ((which == 1) ? P.bk : P.bv);
    P.bcat[i] = bb[l * 256 + col];
  }
  for (int i = gid; i < N_NODES * 256; i += gstride) {
    float v = P.x[i];
    unsigned short h = f2bf(v);
    P.xhi[i] = h;
    P.xlo[i] = f2bf(v - bf2f(h));
  }
  for (int j = b; j < 576; j += nb) {     // 8 x 24 x 3 transpose tiles
    int k0 = (j & 7) * 32;
    int n0g = ((j >> 3) % 24) * 32;
    int l = j / 192;
    int which = n0g >> 8, col0 = n0g & 255;
    const float* W = (which == 0) ? P.Wq : ((which == 1) ? P.Wk : P.Wv);
    int c = t & 31, r = t >> 5;
    __syncthreads();
#pragma unroll
    for (int rr = 0; rr < 4; ++rr) {
      int kk = r + rr * 8;
      tile[kk][c] = W[(size_t)l * 65536 + (size_t)(k0 + kk) * 256 + col0 + c];
    }
    __syncthreads();
    int kk = t & 31, nn0 = t >> 5;
#pragma unroll
    for (int rr = 0; rr < 4; ++rr) {
      int nn = nn0 + rr * 8;
      P.wthi[((size_t)l * 768 + n0g + nn) * 256 + k0 + kk] = f2bf(tile[kk][nn]);
    }
  }
  grid.sync();
  // ---- phase 1: degree count ----
  for (int e = gid; e < N_EDGES; e += gstride) atomicAdd(&P.deg[P.dst[e]], 1);
  grid.sync();
  // ---- phase 2: exclusive scan (block 0, 256 threads) ----
  if (b == 0) {
    const int C = 118;                       // 256*118 = 30208 >= N_NODES
    int base = t * C;
    int sum = 0;
    for (int j = 0; j < C; ++j) {
      int idx = base + j;
      sum += (idx < N_NODES) ? P.deg[idx] : 0;
    }
    int lane = t & 63, wv = t >> 6;
    int s = sum;
#pragma unroll
    for (int off = 1; off < 64; off <<= 1) {
      int t2 = __shfl_up(s, off);
      if (lane >= off) s += t2;
    }
    if (lane == 63) wsum4[wv] = s;
    __syncthreads();
    if (t == 0) {
      int a = 0;
#pragma unroll
      for (int i = 0; i < 4; ++i) { int tmp = wsum4[i]; wsum4[i] = a; a += tmp; }
      P.rowstart[N_NODES] = a;
    }
    __syncthreads();
    int pref = wsum4[wv] + (s - sum);
    for (int j = 0; j < C; ++j) {
      int idx = base + j;
      if (idx < N_NODES) {
        P.rowstart[idx] = pref;
        P.cursor[idx]   = pref;
        pref += P.deg[idx];
      }
    }
  }
  grid.sync();
  // ---- phase 3: scatter packed = src*8 + etype ----
  for (int e = gid; e < N_EDGES; e += gstride) {
    int pos = atomicAdd(&P.cursor[P.dst[e]], 1);
    P.packed[pos] = P.src[e] * NETYPES + P.etype[e];
  }
}

// =====================================================================
// Kernel 2: fused main loop (cooperative, persistent blocks)
//   3 x { gemm (round-6 LDS body, XCD job map) -> sync -> attn } ->
//   pool -> sync -> GRU+FC
// =====================================================================
struct MainArgs {
  unsigned short *xhi, *xlo, *kvb;
  const unsigned short* wthi;
  const float *bcat, *Eemb;
  float *qbuf, *gacc;
  const int *rowstart, *packed, *batch;
  const float *W_ih, *b_ih, *b_hh, *W_fc, *b_fc;
  float* out;
};

#define EDGE_BODY(PK, R8, E4, LS, AX, AY, AZ, AW)                            \
  {                                                                          \
    float ex = E4.x, ey = E4.y, ez = E4.z, ew = E4.w;                        \
    float pp = (bf2f(R8[0]) + ex) * q4.x + (bf2f(R8[2]) + ey) * q4.y +       \
               (bf2f(R8[4]) + ez) * q4.z + (bf2f(R8[6]) + ew) * q4.w;        \
    pp += __shfl_xor(pp, 1); pp += __shfl_xor(pp, 2);                        \
    pp += __shfl_xor(pp, 4); pp += __shfl_xor(pp, 8);                        \
    float e1 = __expf(pp * 0.125f);                                          \
    LS += e1;                                                                \
    AX = fmaf(e1, bf2f(R8[1]) + ex, AX);                                     \
    AY = fmaf(e1, bf2f(R8[3]) + ey, AY);                                     \
    AZ = fmaf(e1, bf2f(R8[5]) + ez, AZ);                                     \
    AW = fmaf(e1, bf2f(R8[7]) + ew, AW);                                     \
  }

__global__ __launch_bounds__(256) void k_main(MainArgs P) {
  cg::grid_group grid = cg::this_grid();
  __shared__ __align__(16) unsigned char smem_raw[24576];
  unsigned short* sAhi = (unsigned short*)smem_raw;
  unsigned short* sAlo = sAhi + 4096;
  unsigned short* sBhi = sAhi + 8192;
  float* ete_s = (float*)smem_raw;          // attn overlay (8 KB)
  int* bsh = (int*)smem_raw;                // pool overlay
  float* gvp = (float*)smem_raw;            // gru overlay
  float* gatesp = gvp + 256;
  float* hp = gatesp + 192;

  int b = blockIdx.x, t = threadIdx.x, nb = gridDim.x;
  int lane = t & 63, wave = t >> 6;

  for (int l = 0; l < NLAYERS; ++l) {
    const unsigned short* Bw = P.wthi + (size_t)l * 768 * 256;
    const float* bcat_l = P.bcat + l * 768;
    // ---------------- gemm phase ----------------
    {
      int x = b & 7, u = b >> 3, stride = nb >> 3;
      int mcount = (235 - x + 7) >> 3;       // rows r = x + 8m, r < 235
      int jobs = mcount * 6;
      int wm = (wave >> 1) * 64, wn = (wave & 1) * 64;
      int quad = lane >> 4, l16 = lane & 15;
      int chunk = lane & 3;
      int srow = wave * 32 + (lane >> 2);
      for (int j = u; j < jobs; j += stride) {
        int row0 = (x + 8 * (j / 6)) * 128;
        int n0 = (j % 6) * 128;
        f32x4 acc[4][4];
#pragma unroll
        for (int i = 0; i < 4; ++i)
#pragma unroll
          for (int jj = 0; jj < 4; ++jj) acc[i][jj] = (f32x4)(0.f);
        for (int k0 = 0; k0 < 256; k0 += 32) {
#pragma unroll
          for (int jj = 0; jj < 2; ++jj) {
            int r = srow + jj * 16;
            int ldsoff = wave * 1024 + jj * 512;
            int garA = row0 + r; if (garA >= N_NODES) garA = N_NODES - 1;
            size_t aoff = (size_t)garA * 256 + k0 + chunk * 8;
            async_g2l(P.xhi + aoff, sAhi + ldsoff);
            async_g2l(P.xlo + aoff, sAlo + ldsoff);
            size_t boff = (size_t)(n0 + r) * 256 + k0 + chunk * 8;
            async_g2l(Bw + boff, sBhi + ldsoff);
          }
          __syncthreads();
          short8 ah[4], al[4], bh[4];
#pragma unroll
          for (int i = 0; i < 4; ++i) {
            int off = (wm + i * 16 + l16) * 32 + quad * 8;
            ah[i] = *(const short8*)(sAhi + off);
            al[i] = *(const short8*)(sAlo + off);
          }
#pragma unroll
          for (int jj = 0; jj < 4; ++jj) {
            int off = (wn + jj * 16 + l16) * 32 + quad * 8;
            bh[jj] = *(const short8*)(sBhi + off);
          }
#pragma unroll
          for (int i = 0; i < 4; ++i)
#pragma unroll
            for (int jj = 0; jj < 4; ++jj) {
              acc[i][jj] = __builtin_amdgcn_mfma_f32_16x16x32_bf16(ah[i], bh[jj], acc[i][jj], 0, 0, 0);
              acc[i][jj] = __builtin_amdgcn_mfma_f32_16x16x32_bf16(al[i], bh[jj], acc[i][jj], 0, 0, 0);
            }
          __syncthreads();
        }
        float bj[4];
#pragma unroll
        for (int jj = 0; jj < 4; ++jj) bj[jj] = bcat_l[n0 + wn + jj * 16 + l16];
#pragma unroll
        for (int i = 0; i < 4; ++i) {
          int rowb = row0 + wm + i * 16 + quad * 4;
#pragma unroll
          for (int r = 0; r < 4; ++r) {
            int grow = rowb + r;
            if (grow < N_NODES) {
#pragma unroll
              for (int jj = 0; jj < 4; ++jj) {
                int col = n0 + wn + l16 + jj * 16;
                float val = acc[i][jj][r] + bj[jj];
                if (col < 256) {
                  P.qbuf[(size_t)grow * 256 + col] = val;
                } else if (col < 512) {
                  P.kvb[(size_t)grow * 512 + (col - 256) * 2] = f2bf(val);      // k
                } else {
                  P.kvb[(size_t)grow * 512 + (col - 512) * 2 + 1] = f2bf(val);  // v
                }
              }
            }
          }
        }
      }
    }
    grid.sync();
    // ---------------- attn phase ----------------
#pragma unroll
    for (int i = 0; i < NETYPES; ++i)
      ete_s[i * 256 + t] = P.Eemb[(size_t)l * NETYPES * 256 + i * 256 + t];
    __syncthreads();
    for (int g = b; g < N_NODES / 4; g += nb) {
      int n = g * 4 + (t >> 6);
      float4 q4 = ((const float4*)(P.qbuf + (size_t)n * 256))[lane];
      int rs = P.rowstart[n], re = P.rowstart[n + 1];
      float l1 = 0.f, ax1 = 0.f, ay1 = 0.f, az1 = 0.f, aw1 = 0.f;
      float l2 = 0.f, ax2 = 0.f, ay2 = 0.f, az2 = 0.f, aw2 = 0.f;
      int i = rs;
      for (; i + 4 <= re; i += 4) {
        int p0 = P.packed[i], p1 = P.packed[i + 1], p2 = P.packed[i + 2], p3 = P.packed[i + 3];
        ushort8 r0 = *(const ushort8*)(P.kvb + (size_t)(p0 >> 3) * 512 + lane * 8);
        ushort8 r1 = *(const ushort8*)(P.kvb + (size_t)(p1 >> 3) * 512 + lane * 8);
        ushort8 r2 = *(const ushort8*)(P.kvb + (size_t)(p2 >> 3) * 512 + lane * 8);
        ushort8 r3 = *(const ushort8*)(P.kvb + (size_t)(p3 >> 3) * 512 + lane * 8);
        float4 e0 = ((const float4*)(ete_s + (p0 & 7) * 256))[lane];
        float4 e1v = ((const float4*)(ete_s + (p1 & 7) * 256))[lane];
        float4 e2 = ((const float4*)(ete_s + (p2 & 7) * 256))[lane];
        float4 e3 = ((const float4*)(ete_s + (p3 & 7) * 256))[lane];
        EDGE_BODY(p0, r0, e0, l1, ax1, ay1, az1, aw1);
        EDGE_BODY(p1, r1, e1v, l2, ax2, ay2, az2, aw2);
        EDGE_BODY(p2, r2, e2, l1, ax1, ay1, az1, aw1);
        EDGE_BODY(p3, r3, e3, l2, ax2, ay2, az2, aw2);
      }
      for (; i < re; ++i) {
        int p0 = P.packed[i];
        ushort8 r0 = *(const ushort8*)(P.kvb + (size_t)(p0 >> 3) * 512 + lane * 8);
        float4 e0 = ((const float4*)(ete_s + (p0 & 7) * 256))[lane];
        EDGE_BODY(p0, r0, e0, l1, ax1, ay1, az1, aw1);
      }
      float ls = l1 + l2;
      float ax = ax1 + ax2, ay = ay1 + ay2, az = az1 + az2, aw = aw1 + aw2;
      float inv = 1.f / (ls + 1e-16f);
      float4 o;
      o.x = ax * inv; o.y = ay * inv; o.z = az * inv; o.w = aw * inv;
      o.x = o.x > 0.f ? o.x : expm1f(o.x);
      o.y = o.y > 0.f ? o.y : expm1f(o.y);
      o.z = o.z > 0.f ? o.z : expm1f(o.z);
      o.w = o.w > 0.f ? o.w : expm1f(o.w);
      unsigned short h0 = f2bf(o.x), h1 = f2bf(o.y), h2 = f2bf(o.z), h3 = f2bf(o.w);
      ushort4 hv, lv;
      hv.x = h0; hv.y = h1; hv.z = h2; hv.w = h3;
      lv.x = f2bf(o.x - bf2f(h0)); lv.y = f2bf(o.y - bf2f(h1));
      lv.z = f2bf(o.z - bf2f(h2)); lv.w = f2bf(o.w - bf2f(h3));
      size_t base_o = (size_t)n * 256 + lane * 4;
      *(ushort4*)(P.xhi + base_o) = hv;
      *(ushort4*)(P.xlo + base_o) = lv;
    }
    grid.sync();
  }
  // ---------------- pool phase ----------------
  for (int c = b; c < (N_NODES + 127) / 128; c += nb) {
    int base = c * 128;
    int end = base + 128; if (end > N_NODES) end = N_NODES;
    __syncthreads();
    if (t < 128 && base + t < N_NODES) bsh[t] = P.batch[base + t];
    __syncthreads();
    float acc = 0.f;
    int cur = bsh[0];
    for (int n = base; n < end; ++n) {
      int g2 = bsh[n - base];
      if (g2 != cur) { atomicAdd(&P.gacc[cur * 256 + t], acc); acc = 0.f; cur = g2; }
      size_t idx = (size_t)n * 256 + t;
      acc += bf2f(P.xhi[idx]) + bf2f(P.xlo[idx]);
    }
    atomicAdd(&P.gacc[cur * 256 + t], acc);
  }
  grid.sync();
  // ---------------- GRU + FC phase ----------------
  for (int gr = b; gr < NGRAPHS; gr += nb) {
    // count nodes of graph gr by binary search on sorted batch
    int lo = 0, hi = N_NODES;
    while (lo < hi) { int mid = (lo + hi) >> 1; if (P.batch[mid] < gr) lo = mid + 1; else hi = mid; }
    int s0 = lo;
    lo = 0; hi = N_NODES;
    while (lo < hi) { int mid = (lo + hi) >> 1; if (P.batch[mid] < gr + 1) lo = mid + 1; else hi = mid; }
    int e0 = lo;
    float cnum = (e0 > s0) ? (float)(e0 - s0) : 1.f;
    __syncthreads();
    gvp[t] = P.gacc[gr * 256 + t] / cnum;
    __syncthreads();
    if (t < 192) {
      const float* wr = P.W_ih + t * 256;
      float s = P.b_ih[t];
      for (int k = 0; k < 256; ++k) s = fmaf(gvp[k], wr[k], s);
      gatesp[t] = s;
    }
    __syncthreads();
    if (t < 64) {
      float r  = 1.f / (1.f + expf(-(gatesp[t] + P.b_hh[t])));
      float z  = 1.f / (1.f + expf(-(gatesp[64 + t] + P.b_hh[64 + t])));
      float nn = tanhf(gatesp[128 + t] + r * P.b_hh[128 + t]);
      hp[t] = (1.f - z) * nn;
    }
    __syncthreads();
    if (t < 2) {
      const float* wr = P.W_fc + t * 64;
      float s = P.b_fc[t];
      for (int k = 0; k < 64; ++k) s = fmaf(hp[k], wr[k], s);
      P.out[gr * 2 + t] = s;
    }
    __syncthreads();
  }
}

extern "C" void kernel_launch(void* const* d_in, const int* in_sizes, int n_in,
                              void* d_out, int out_size, void* d_ws, size_t ws_size,
                              hipStream_t stream) {
  const float* x     = (const float*)d_in[0];
  const int* edge_index = (const int*)d_in[1];
  const int* batch   = (const int*)d_in[2];
  const int* etype   = (const int*)d_in[3];
  const float* Wq    = (const float*)d_in[4];
  const float* bq    = (const float*)d_in[5];
  const float* Wk    = (const float*)d_in[6];
  const float* bk    = (const float*)d_in[7];
  const float* Wv    = (const float*)d_in[8];
  const float* bv    = (const float*)d_in[9];
  const float* Eemb  = (const float*)d_in[10];
  const float* W_ih  = (const float*)d_in[11];
  const float* b_ih  = (const float*)d_in[12];
  const float* b_hh  = (const float*)d_in[14];
  const float* W_fc  = (const float*)d_in[15];
  const float* b_fc  = (const float*)d_in[16];
  float* out = (float*)d_out;

  const int* src = edge_index;
  const int* dst = edge_index + N_EDGES;

  float* qbuf  = (float*)d_ws;                             // N*256 f32
  float* gacc  = qbuf + (size_t)N_NODES * 256;             // 64*256
  float* bcat  = gacc + NGRAPHS * 256;                     // 3*768
  unsigned short* kvb  = (unsigned short*)(bcat + NLAYERS * 768);  // N*512 interleaved
  unsigned short* xhi  = kvb + (size_t)N_NODES * 512;      // N*256
  unsigned short* xlo  = xhi + (size_t)N_NODES * 256;
  unsigned short* wthi = xlo + (size_t)N_NODES * 256;      // 3*768*256
  int* deg      = (int*)(wthi + (size_t)NLAYERS * 768 * 256);
  int* rowstart = deg + N_NODES;
  int* cursor   = rowstart + N_NODES + 1;
  int* packed   = cursor + N_NODES;

  PreArgs PA;
  PA.src = src; PA.dst = dst; PA.etype = etype;
  PA.Wq = Wq; PA.Wk = Wk; PA.Wv = Wv; PA.bq = bq; PA.bk = bk; PA.bv = bv; PA.x = x;
  PA.deg = deg; PA.rowstart = rowstart; PA.cursor = cursor; PA.packed = packed;
  PA.wthi = wthi; PA.xhi = xhi; PA.xlo = xlo; PA.bcat = bcat; PA.gacc = gacc;

  MainArgs MA;
  MA.xhi = xhi; MA.xlo = xlo; MA.kvb = kvb; MA.wthi = wthi;
  MA.bcat = bcat; MA.Eemb = Eemb; MA.qbuf = qbuf; MA.gacc = gacc;
  MA.rowstart = rowstart; MA.packed = packed; MA.batch = batch;
  MA.W_ih = W_ih; MA.b_ih = b_ih; MA.b_hh = b_hh; MA.W_fc = W_fc; MA.b_fc = b_fc;
  MA.out = out;

  int mbPre = 0, mbMain = 0;
  hipOccupancyMaxActiveBlocksPerMultiprocessor(&mbPre, (const void*)k_pre, 256, 0);
  hipOccupancyMaxActiveBlocksPerMultiprocessor(&mbMain, (const void*)k_main, 256, 0);
  if (mbPre < 1) mbPre = 1;
  if (mbMain < 1) mbMain = 1;
  int gridPre = mbPre * 256; if (gridPre > 512) gridPre = 512;
  int gridMain = mbMain * 256; if (gridMain > 768) gridMain = 768;
  gridMain &= ~7; if (gridMain < 8) gridMain = 8;

  void* argsPre[]  = { &PA };
  void* argsMain[] = { &MA };
  hipLaunchCooperativeKernel((const void*)k_pre, dim3(gridPre), dim3(256),
                             argsPre, 0, stream);
  hipLaunchCooperativeKernel((const void*)k_main, dim3(gridMain), dim3(256),
                             argsMain, 0, stream);
}

// Round 9
// 527.413 us; speedup vs baseline: 2.3115x; 2.3115x over previous
//
#include <hip/hip_runtime.h>
#include <math.h>

#define N_NODES 30000
#define N_EDGES 240000
#define NETYPES 8
#define NGRAPHS 64
#define NLAYERS 3
#define NBLK 1880          // ceil(30080/16) node blocks for packed A
#define WLAYER 196608      // 768*256 packed weight elems per layer

typedef __attribute__((ext_vector_type(8))) short short8;
typedef __attribute__((ext_vector_type(8))) unsigned short ushort8;
typedef __attribute__((ext_vector_type(4))) float f32x4;

// ---- bf16 split helpers (round-to-nearest-even) ----
__device__ __forceinline__ unsigned short f2bf(float f) {
  union { float f; unsigned u; } v; v.f = f;
  unsigned r = v.u + 0x7FFF + ((v.u >> 16) & 1);
  return (unsigned short)(r >> 16);
}
__device__ __forceinline__ float bf2f(unsigned short h) {
  union { unsigned u; float f; } v; v.u = ((unsigned)h) << 16;
  return v.f;
}

// MFMA-fragment-packed layout: (row,k) -> offset. A wave fragment load is
// base + lane*8 shorts (lane = ((k%32)/8)*16 + row%16) => coalesced 16B/lane.
__device__ __forceinline__ int pk_off(int row, int k) {
  return (((row >> 4) * 8 + (k >> 5)) << 9) + (((k & 31) >> 3) << 7) +
         ((row & 15) << 3) + (k & 7);
}

// =============== prologue: zero + bcat + x split (packed) + W cvt (packed) ===============
__global__ __launch_bounds__(256) void k_prep(
    const float* __restrict__ x,
    const float* __restrict__ Wq, const float* __restrict__ Wk, const float* __restrict__ Wv,
    const float* __restrict__ bq, const float* __restrict__ bk, const float* __restrict__ bv,
    unsigned short* __restrict__ xhi, unsigned short* __restrict__ xlo,
    unsigned short* __restrict__ wthi, float* __restrict__ bcat,
    float* __restrict__ gacc, int* __restrict__ deg) {
  int b = blockIdx.x, t = threadIdx.x;
  if (b < 576) {
    // weight transpose tile 32x32 -> packed bf16
    __shared__ float tile[32][33];
    int k0 = (b & 7) * 32;
    int n0g = ((b >> 3) % 24) * 32;
    int l = b / 192;
    int which = n0g >> 8, col0 = n0g & 255;
    const float* W = (which == 0) ? Wq : ((which == 1) ? Wk : Wv);
    int c = t & 31, r = t >> 5;
#pragma unroll
    for (int rr = 0; rr < 4; ++rr) {
      int kk = r + rr * 8;
      tile[kk][c] = W[(size_t)l * 65536 + (size_t)(k0 + kk) * 256 + col0 + c];
    }
    __syncthreads();
    int kk = t & 31, nn0 = t >> 5;
#pragma unroll
    for (int rr = 0; rr < 4; ++rr) {
      int nn = nn0 + rr * 8;
      wthi[l * WLAYER + pk_off(n0g + nn, k0 + kk)] = f2bf(tile[kk][nn]);
    }
  } else {
    int gid = (b - 576) * 256 + t;
    int gstride = (gridDim.x - 576) * 256;
    for (int i = gid; i < N_NODES; i += gstride) deg[i] = 0;
    for (int i = gid; i < NGRAPHS * 256; i += gstride) gacc[i] = 0.f;
    for (int i = gid; i < NLAYERS * 768; i += gstride) {
      int n = i % 768, l = i / 768;
      int which = n >> 8, col = n & 255;
      const float* bb = (which == 0) ? bq : ((which == 1) ? bk : bv);
      bcat[i] = bb[l * 256 + col];
    }
    // x split: each thread handles 8 consecutive channels
    for (int i = gid; i < N_NODES * 32; i += gstride) {
      int n = i >> 5, c0 = (i & 31) << 3;
      const float* xp = x + (size_t)n * 256 + c0;
      unsigned short hv[8], lv[8];
#pragma unroll
      for (int e = 0; e < 8; ++e) {
        float v = xp[e];
        unsigned short h = f2bf(v);
        hv[e] = h;
        lv[e] = f2bf(v - bf2f(h));
      }
      int off = pk_off(n, c0);
      *(ushort8*)(xhi + off) = *(ushort8*)hv;
      *(ushort8*)(xlo + off) = *(ushort8*)lv;
    }
  }
}

// =============== CSR build ===============
__global__ void k_count_deg(const int* __restrict__ dst, int* __restrict__ deg) {
  int e = blockIdx.x * blockDim.x + threadIdx.x;
  if (e < N_EDGES) atomicAdd(&deg[dst[e]], 1);
}

__global__ __launch_bounds__(1024) void k_scan(const int* __restrict__ deg,
                                               int* __restrict__ rowstart,
                                               int* __restrict__ cursor) {
  const int C = 30;
  int tid = threadIdx.x;
  int base = tid * C;
  int vals[C];
  int sum = 0;
#pragma unroll
  for (int j = 0; j < C; ++j) {
    int idx = base + j;
    int v = (idx < N_NODES) ? deg[idx] : 0;
    vals[j] = sum;
    sum += v;
  }
  int lane = tid & 63, wv = tid >> 6;
  int s = sum;
#pragma unroll
  for (int off = 1; off < 64; off <<= 1) {
    int t2 = __shfl_up(s, off);
    if (lane >= off) s += t2;
  }
  __shared__ int wsum[16];
  if (lane == 63) wsum[wv] = s;
  __syncthreads();
  if (tid == 0) {
    int a = 0;
#pragma unroll
    for (int i = 0; i < 16; ++i) { int t2 = wsum[i]; wsum[i] = a; a += t2; }
    rowstart[N_NODES] = a;
  }
  __syncthreads();
  int texcl = wsum[wv] + (s - sum);
#pragma unroll
  for (int j = 0; j < C; ++j) {
    int idx = base + j;
    if (idx < N_NODES) {
      int p = texcl + vals[j];
      rowstart[idx] = p;
      cursor[idx]   = p;
    }
  }
}

__global__ void k_scatter(const int* __restrict__ src, const int* __restrict__ dst,
                          const int* __restrict__ etype, int* __restrict__ cursor,
                          int* __restrict__ packed) {
  int e = blockIdx.x * blockDim.x + threadIdx.x;
  if (e < N_EDGES) {
    int p = atomicAdd(&cursor[dst[e]], 1);
    packed[p] = src[e] * NETYPES + etype[e];
  }
}

// =============== barrier-free packed-fragment MFMA GEMM ===============
// XCD-swizzled grid (round-6 win: FETCH 92->18MB). Fragments loaded straight
// from packed global buffers at base+lane*8 => one coalesced dwordx4 per
// fragment. No LDS, no __syncthreads, no vmcnt(0) drains.
__global__ __launch_bounds__(256) void k_gemm_mfma(
    const unsigned short* __restrict__ Ahi, const unsigned short* __restrict__ Alo,
    const unsigned short* __restrict__ Bw,
    const float* __restrict__ bcat, float* __restrict__ qbuf,
    unsigned short* __restrict__ kvb) {
  int x = blockIdx.x & 7, j0 = blockIdx.x >> 3;
  int rg = j0 / 6, c0 = j0 % 6;
  int r0 = rg * 8 + x;
  if (r0 >= 235) return;
  int row0 = r0 * 128;
  int n0 = c0 * 128;

  int tid = threadIdx.x;
  int lane = tid & 63, wave = tid >> 6;
  int wm = (wave >> 1) * 64, wn = (wave & 1) * 64;
  int quad = lane >> 4, l16 = lane & 15;

  const unsigned short* pAh = Ahi + ((((row0 + wm) >> 4) * 8) << 9) + lane * 8;
  const unsigned short* pAl = Alo + ((((row0 + wm) >> 4) * 8) << 9) + lane * 8;
  const unsigned short* pB  = Bw  + ((((n0 + wn) >> 4) * 8) << 9) + lane * 8;

  f32x4 acc[4][4];
#pragma unroll
  for (int i = 0; i < 4; ++i)
#pragma unroll
    for (int j = 0; j < 4; ++j) acc[i][j] = (f32x4)(0.f);

#pragma unroll 2
  for (int kc = 0; kc < 8; ++kc) {
    short8 ah[4], al[4], bh[4];
#pragma unroll
    for (int i = 0; i < 4; ++i) {
      ah[i] = *(const short8*)(pAh + i * 4096 + kc * 512);
      al[i] = *(const short8*)(pAl + i * 4096 + kc * 512);
      bh[i] = *(const short8*)(pB  + i * 4096 + kc * 512);
    }
#pragma unroll
    for (int i = 0; i < 4; ++i)
#pragma unroll
      for (int j = 0; j < 4; ++j) {
        acc[i][j] = __builtin_amdgcn_mfma_f32_16x16x32_bf16(ah[i], bh[j], acc[i][j], 0, 0, 0);
        acc[i][j] = __builtin_amdgcn_mfma_f32_16x16x32_bf16(al[i], bh[j], acc[i][j], 0, 0, 0);
      }
  }

  float bj[4];
#pragma unroll
  for (int j = 0; j < 4; ++j) bj[j] = bcat[n0 + wn + j * 16 + l16];
#pragma unroll
  for (int i = 0; i < 4; ++i) {
    int rowb = row0 + wm + i * 16 + quad * 4;
#pragma unroll
    for (int r = 0; r < 4; ++r) {
      int grow = rowb + r;
      if (grow < N_NODES) {
#pragma unroll
        for (int j = 0; j < 4; ++j) {
          int col = n0 + wn + l16 + j * 16;
          float val = acc[i][j][r] + bj[j];
          if (col < 256) {
            qbuf[(size_t)grow * 256 + col] = val;
          } else if (col < 512) {
            kvb[(size_t)grow * 512 + (col - 256) * 2] = f2bf(val);       // k
          } else {
            kvb[(size_t)grow * 512 + (col - 512) * 2 + 1] = f2bf(val);   // v
          }
        }
      }
    }
  }
}

// =============== per-dst-node edge attention (persistent-lite grid-stride) ===============
#define EDGE_BODY(PK, R8, E4, LS, AX, AY, AZ, AW)                            \
  {                                                                          \
    float ex = E4.x, ey = E4.y, ez = E4.z, ew = E4.w;                        \
    float pp = (bf2f(R8[0]) + ex) * q4.x + (bf2f(R8[2]) + ey) * q4.y +       \
               (bf2f(R8[4]) + ez) * q4.z + (bf2f(R8[6]) + ew) * q4.w;        \
    pp += __shfl_xor(pp, 1); pp += __shfl_xor(pp, 2);                        \
    pp += __shfl_xor(pp, 4); pp += __shfl_xor(pp, 8);                        \
    float e1 = __expf(pp * 0.125f);                                          \
    LS += e1;                                                                \
    AX = fmaf(e1, bf2f(R8[1]) + ex, AX);                                     \
    AY = fmaf(e1, bf2f(R8[3]) + ey, AY);                                     \
    AZ = fmaf(e1, bf2f(R8[5]) + ez, AZ);                                     \
    AW = fmaf(e1, bf2f(R8[7]) + ew, AW);                                     \
  }

__global__ __launch_bounds__(256) void k_attn(
    const float* __restrict__ qbuf, const unsigned short* __restrict__ kvb,
    const int* __restrict__ rowstart, const int* __restrict__ packed,
    const float* __restrict__ Eemb_l,
    unsigned short* __restrict__ xhi, unsigned short* __restrict__ xlo) {
  __shared__ float ete_s[NETYPES * 256];
  int t = threadIdx.x;
#pragma unroll
  for (int i = 0; i < NETYPES; ++i) ete_s[i * 256 + t] = Eemb_l[i * 256 + t];
  __syncthreads();
  int lane = t & 63, slot = t >> 6;
  int nb = gridDim.x;
  for (int g = blockIdx.x; g < N_NODES / 4; g += nb) {
    int n = g * 4 + slot;
    float4 q4 = ((const float4*)(qbuf + (size_t)n * 256))[lane];
    int rs = rowstart[n], re = rowstart[n + 1];
    float l1 = 0.f, ax1 = 0.f, ay1 = 0.f, az1 = 0.f, aw1 = 0.f;
    float l2 = 0.f, ax2 = 0.f, ay2 = 0.f, az2 = 0.f, aw2 = 0.f;
    int i = rs;
    for (; i + 4 <= re; i += 4) {
      int p0 = packed[i], p1 = packed[i + 1], p2 = packed[i + 2], p3 = packed[i + 3];
      ushort8 r0 = *(const ushort8*)(kvb + (size_t)(p0 >> 3) * 512 + lane * 8);
      ushort8 r1 = *(const ushort8*)(kvb + (size_t)(p1 >> 3) * 512 + lane * 8);
      ushort8 r2 = *(const ushort8*)(kvb + (size_t)(p2 >> 3) * 512 + lane * 8);
      ushort8 r3 = *(const ushort8*)(kvb + (size_t)(p3 >> 3) * 512 + lane * 8);
      float4 e0 = ((const float4*)(ete_s + (p0 & 7) * 256))[lane];
      float4 e1v = ((const float4*)(ete_s + (p1 & 7) * 256))[lane];
      float4 e2 = ((const float4*)(ete_s + (p2 & 7) * 256))[lane];
      float4 e3 = ((const float4*)(ete_s + (p3 & 7) * 256))[lane];
      EDGE_BODY(p0, r0, e0, l1, ax1, ay1, az1, aw1);
      EDGE_BODY(p1, r1, e1v, l2, ax2, ay2, az2, aw2);
      EDGE_BODY(p2, r2, e2, l1, ax1, ay1, az1, aw1);
      EDGE_BODY(p3, r3, e3, l2, ax2, ay2, az2, aw2);
    }
    for (; i < re; ++i) {
      int p0 = packed[i];
      ushort8 r0 = *(const ushort8*)(kvb + (size_t)(p0 >> 3) * 512 + lane * 8);
      float4 e0 = ((const float4*)(ete_s + (p0 & 7) * 256))[lane];
      EDGE_BODY(p0, r0, e0, l1, ax1, ay1, az1, aw1);
    }
    float ls = l1 + l2;
    float ax = ax1 + ax2, ay = ay1 + ay2, az = az1 + az2, aw = aw1 + aw2;
    float inv = 1.f / (ls + 1e-16f);
    float4 o;
    o.x = ax * inv; o.y = ay * inv; o.z = az * inv; o.w = aw * inv;
    o.x = o.x > 0.f ? o.x : expm1f(o.x);
    o.y = o.y > 0.f ? o.y : expm1f(o.y);
    o.z = o.z > 0.f ? o.z : expm1f(o.z);
    o.w = o.w > 0.f ? o.w : expm1f(o.w);
    unsigned short h0 = f2bf(o.x), h1 = f2bf(o.y), h2 = f2bf(o.z), h3 = f2bf(o.w);
    unsigned short hv[4], lv[4];
    hv[0] = h0; hv[1] = h1; hv[2] = h2; hv[3] = h3;
    lv[0] = f2bf(o.x - bf2f(h0)); lv[1] = f2bf(o.y - bf2f(h1));
    lv[2] = f2bf(o.z - bf2f(h2)); lv[3] = f2bf(o.w - bf2f(h3));
    int off = pk_off(n, lane * 4);
    *(ushort4*)(xhi + off) = *(ushort4*)hv;
    *(ushort4*)(xlo + off) = *(ushort4*)lv;
  }
}

// =============== parallel mean pool (packed x read) ===============
__global__ __launch_bounds__(256) void k_pool_partial(
    const unsigned short* __restrict__ xhi, const unsigned short* __restrict__ xlo,
    const int* __restrict__ batch, float* __restrict__ gacc) {
  int t = threadIdx.x;
  int base = blockIdx.x * 128;
  int end = base + 128; if (end > N_NODES) end = N_NODES;
  __shared__ int bsh[128];
  if (t < 128 && base + t < N_NODES) bsh[t] = batch[base + t];
  __syncthreads();
  int kc = t >> 5, quad_off = ((t & 31) >> 3) << 7, e = t & 7;
  float acc = 0.f;
  int cur = bsh[0];
  for (int n = base; n < end; ++n) {
    int g = bsh[n - base];
    if (g != cur) {
      atomicAdd(&gacc[cur * 256 + t], acc);
      acc = 0.f; cur = g;
    }
    int idx = (((n >> 4) * 8 + kc) << 9) + quad_off + ((n & 15) << 3) + e;
    acc += bf2f(xhi[idx]) + bf2f(xlo[idx]);
  }
  atomicAdd(&gacc[cur * 256 + t], acc);
}

// =============== GRU (h0=0) + FC ===============
__device__ inline int lower_bound_dev(const int* a, int n, int val) {
  int lo = 0, hi = n;
  while (lo < hi) {
    int mid = (lo + hi) >> 1;
    if (a[mid] < val) lo = mid + 1; else hi = mid;
  }
  return lo;
}

__global__ __launch_bounds__(256) void k_gru_fc(
    const float* __restrict__ gacc, const int* __restrict__ batch,
    const float* __restrict__ W_ih, const float* __restrict__ b_ih,
    const float* __restrict__ b_hh, const float* __restrict__ W_fc,
    const float* __restrict__ b_fc, float* __restrict__ out) {
  __shared__ float gv[256];
  __shared__ float gates[192];
  __shared__ float h[64];
  int gr = blockIdx.x, t = threadIdx.x;
  int s0 = lower_bound_dev(batch, N_NODES, gr);
  int e0 = lower_bound_dev(batch, N_NODES, gr + 1);
  float c = (e0 > s0) ? (float)(e0 - s0) : 1.f;
  gv[t] = gacc[gr * 256 + t] / c;
  __syncthreads();
  if (t < 192) {
    const float* wr = W_ih + t * 256;
    float s = b_ih[t];
    for (int k = 0; k < 256; ++k) s = fmaf(gv[k], wr[k], s);
    gates[t] = s;
  }
  __syncthreads();
  if (t < 64) {
    float r  = 1.f / (1.f + expf(-(gates[t] + b_hh[t])));
    float z  = 1.f / (1.f + expf(-(gates[64 + t] + b_hh[64 + t])));
    float nn = tanhf(gates[128 + t] + r * b_hh[128 + t]);
    h[t] = (1.f - z) * nn;
  }
  __syncthreads();
  if (t < 2) {
    const float* wr = W_fc + t * 64;
    float s = b_fc[t];
    for (int k = 0; k < 64; ++k) s = fmaf(h[k], wr[k], s);
    out[gr * 2 + t] = s;
  }
}

extern "C" void kernel_launch(void* const* d_in, const int* in_sizes, int n_in,
                              void* d_out, int out_size, void* d_ws, size_t ws_size,
                              hipStream_t stream) {
  const float* x     = (const float*)d_in[0];
  const int* edge_index = (const int*)d_in[1];
  const int* batch   = (const int*)d_in[2];
  const int* etype   = (const int*)d_in[3];
  const float* Wq    = (const float*)d_in[4];
  const float* bq    = (const float*)d_in[5];
  const float* Wk    = (const float*)d_in[6];
  const float* bk    = (const float*)d_in[7];
  const float* Wv    = (const float*)d_in[8];
  const float* bv    = (const float*)d_in[9];
  const float* Eemb  = (const float*)d_in[10];
  const float* W_ih  = (const float*)d_in[11];
  const float* b_ih  = (const float*)d_in[12];
  const float* b_hh  = (const float*)d_in[14];
  const float* W_fc  = (const float*)d_in[15];
  const float* b_fc  = (const float*)d_in[16];
  float* out = (float*)d_out;

  const int* src = edge_index;
  const int* dst = edge_index + N_EDGES;

  float* qbuf  = (float*)d_ws;                             // N*256 f32
  float* gacc  = qbuf + (size_t)N_NODES * 256;             // 64*256
  float* bcat  = gacc + NGRAPHS * 256;                     // 3*768
  unsigned short* kvb  = (unsigned short*)(bcat + NLAYERS * 768);  // N*512 interleaved
  unsigned short* xhi  = kvb + (size_t)N_NODES * 512;      // NBLK*4096 packed
  unsigned short* xlo  = xhi + (size_t)NBLK * 4096;
  unsigned short* wthi = xlo + (size_t)NBLK * 4096;        // 3*WLAYER packed
  int* deg      = (int*)(wthi + (size_t)NLAYERS * WLAYER);
  int* rowstart = deg + N_NODES;
  int* cursor   = rowstart + N_NODES + 1;
  int* packed   = cursor + N_NODES;

  k_prep<<<1600, 256, 0, stream>>>(x, Wq, Wk, Wv, bq, bk, bv,
                                   xhi, xlo, wthi, bcat, gacc, deg);
  k_count_deg<<<(N_EDGES + 255) / 256, 256, 0, stream>>>(dst, deg);
  k_scan<<<1, 1024, 0, stream>>>(deg, rowstart, cursor);
  k_scatter<<<(N_EDGES + 255) / 256, 256, 0, stream>>>(src, dst, etype, cursor, packed);

  for (int l = 0; l < NLAYERS; ++l) {
    k_gemm_mfma<<<1440, 256, 0, stream>>>(
        xhi, xlo, wthi + (size_t)l * WLAYER,
        bcat + l * 768, qbuf, kvb);
    k_attn<<<2048, 256, 0, stream>>>(qbuf, kvb, rowstart, packed,
                                     Eemb + (size_t)l * NETYPES * 256, xhi, xlo);
  }
  k_pool_partial<<<(N_NODES + 127) / 128, 256, 0, stream>>>(xhi, xlo, batch, gacc);
  k_gru_fc<<<NGRAPHS, 256, 0, stream>>>(gacc, batch, W_ih, b_ih, b_hh, W_fc, b_fc, out);
}